// Round 1
// baseline (258.567 us; speedup 1.0000x reference)
//
#include <hip/hip_runtime.h>
#include <cstdint>
#include <cstddef>

#define Bc 8
#define Sc 2048
#define Dc 512

typedef float f32x4 __attribute__((ext_vector_type(4)));
typedef __bf16 bf16x8 __attribute__((ext_vector_type(8)));

__device__ __forceinline__ void gload_lds16(const void* g, void* l) {
    __builtin_amdgcn_global_load_lds((const __attribute__((address_space(1))) void*)g,
                                     (__attribute__((address_space(3))) void*)l, 16, 0, 0);
}

__device__ __forceinline__ f32x4 mfma16x16x32(bf16x8 a, bf16x8 b, f32x4 c) {
    return __builtin_amdgcn_mfma_f32_16x16x32_bf16(a, b, c, 0, 0, 0);
}

// ---- convert W_in / W_out to bf16 (512*512 each) ----
__global__ void k_convert_w(const float* __restrict__ wi, const float* __restrict__ wo,
                            __bf16* __restrict__ wib, __bf16* __restrict__ wob) {
    int i = blockIdx.x * 256 + threadIdx.x;   // grid sized exactly Dc*Dc/256
    wib[i] = (__bf16)wi[i];
    wob[i] = (__bf16)wo[i];
}

// ---- bf16 GEMM: C(fp32)[M,N] = A[M,K] * Bt[N,K]^T, tile 128x128x64, 4 waves ----
__global__ __launch_bounds__(256) void k_gemm_bf16(
        const __bf16* __restrict__ A, const __bf16* __restrict__ Bt, float* __restrict__ C,
        int lda, int ldb, int ldc, int K,
        size_t aOffZ, size_t bOffZ, size_t cOffZ)
{
    __shared__ __bf16 smem[2 * 128 * 64];
    __bf16* As = smem;
    __bf16* Bs = smem + 128 * 64;
    const int tid  = threadIdx.x;
    const int wave = tid >> 6, lane = tid & 63;
    const int waveM = wave >> 1, waveN = wave & 1;
    const int row0 = blockIdx.y * 128;
    const int col0 = blockIdx.x * 128;
    A  += (size_t)blockIdx.z * aOffZ;
    Bt += (size_t)blockIdx.z * bOffZ;
    C  += (size_t)blockIdx.z * cOffZ;

    f32x4 acc[4][4] = {};

    for (int k0 = 0; k0 < K; k0 += 64) {
        // stage A,B [128][64] bf16; linear LDS dest, XOR-swizzled global source (16B chunks)
        #pragma unroll
        for (int i = 0; i < 4; ++i) {
            int flat = i * 2048 + wave * 512 + lane * 8;
            int r  = flat >> 6;
            int cc = (flat >> 3) & 7;
            int gc = (cc ^ (r & 7)) << 3;
            gload_lds16(A  + (size_t)(row0 + r) * lda + k0 + gc, As + i * 2048 + wave * 512);
            gload_lds16(Bt + (size_t)(col0 + r) * ldb + k0 + gc, Bs + i * 2048 + wave * 512);
        }
        __syncthreads();
        #pragma unroll
        for (int ks = 0; ks < 2; ++ks) {
            const int kc = ks * 4 + (lane >> 4);   // 8-elem chunk index
            bf16x8 av[4], bv[4];
            #pragma unroll
            for (int mi = 0; mi < 4; ++mi) {
                int r = waveM * 64 + mi * 16 + (lane & 15);
                av[mi] = *(const bf16x8*)&As[r * 64 + ((kc ^ (r & 7)) << 3)];
            }
            #pragma unroll
            for (int ni = 0; ni < 4; ++ni) {
                int r = waveN * 64 + ni * 16 + (lane & 15);
                bv[ni] = *(const bf16x8*)&Bs[r * 64 + ((kc ^ (r & 7)) << 3)];
            }
            #pragma unroll
            for (int mi = 0; mi < 4; ++mi)
                #pragma unroll
                for (int ni = 0; ni < 4; ++ni)
                    acc[mi][ni] = mfma16x16x32(av[mi], bv[ni], acc[mi][ni]);
        }
        __syncthreads();
    }

    const int rb = (lane >> 4) << 2;
    const int cb = lane & 15;
    #pragma unroll
    for (int mi = 0; mi < 4; ++mi)
        #pragma unroll
        for (int ni = 0; ni < 4; ++ni) {
            int gr = row0 + waveM * 64 + mi * 16 + rb;
            int gc = col0 + waveN * 64 + ni * 16 + cb;
            #pragma unroll
            for (int rr = 0; rr < 4; ++rr)
                C[(size_t)(gr + rr) * ldc + gc] = acc[mi][ni][rr];
        }
}

// ---- fp32-A, bf16-B GEMM. MODE 0: write bf16 C and bf16 C^T (c-projection)
//                           MODE 1: write bf16 tanh(C)        (attn @ c)     ----
template <int MODE>
__global__ __launch_bounds__(256) void k_gemm_f32a(
        const float* __restrict__ A, const __bf16* __restrict__ Bt,
        __bf16* __restrict__ Cb, __bf16* __restrict__ CTb,
        int lda, int ldb, int K, size_t aOffZ, size_t bOffZ, int crowPerZ)
{
    __shared__ char smem[49152];
    float*  Asf = (float*)smem;              // [128][64] fp32 (32 KiB)
    __bf16* Bs  = (__bf16*)(smem + 32768);   // [128][64] bf16 (16 KiB)
    const int tid  = threadIdx.x;
    const int wave = tid >> 6, lane = tid & 63;
    const int waveM = wave >> 1, waveN = wave & 1;
    const int row0 = blockIdx.y * 128;
    const int col0 = blockIdx.x * 128;
    A  += (size_t)blockIdx.z * aOffZ;
    Bt += (size_t)blockIdx.z * bOffZ;
    const int crow0 = blockIdx.z * crowPerZ + row0;

    f32x4 acc[4][4] = {};

    for (int k0 = 0; k0 < K; k0 += 64) {
        #pragma unroll
        for (int i = 0; i < 8; ++i) {        // A fp32: 16 chunks/row of 4 floats
            int flat = i * 1024 + wave * 256 + lane * 4;
            int r  = flat >> 6;
            int cc = (flat >> 2) & 15;
            int gc = (cc ^ (r & 15)) << 2;
            gload_lds16(A + (size_t)(row0 + r) * lda + k0 + gc, Asf + i * 1024 + wave * 256);
        }
        #pragma unroll
        for (int i = 0; i < 4; ++i) {        // B bf16: 8 chunks/row of 8 elems
            int flat = i * 2048 + wave * 512 + lane * 8;
            int r  = flat >> 6;
            int cc = (flat >> 3) & 7;
            int gc = (cc ^ (r & 7)) << 3;
            gload_lds16(Bt + (size_t)(col0 + r) * ldb + k0 + gc, Bs + i * 2048 + wave * 512);
        }
        __syncthreads();
        #pragma unroll
        for (int ks = 0; ks < 2; ++ks) {
            const int kc8 = ks * 4 + (lane >> 4);
            const int kc4 = kc8 << 1;
            bf16x8 av[4], bv[4];
            #pragma unroll
            for (int mi = 0; mi < 4; ++mi) {
                int r  = waveM * 64 + mi * 16 + (lane & 15);
                int r4 = r & 15;
                f32x4 lo = *(const f32x4*)&Asf[r * 64 + (((kc4    ) ^ r4) << 2)];
                f32x4 hi = *(const f32x4*)&Asf[r * 64 + (((kc4 + 1) ^ r4) << 2)];
                bf16x8 a;
                a[0] = (__bf16)lo[0]; a[1] = (__bf16)lo[1]; a[2] = (__bf16)lo[2]; a[3] = (__bf16)lo[3];
                a[4] = (__bf16)hi[0]; a[5] = (__bf16)hi[1]; a[6] = (__bf16)hi[2]; a[7] = (__bf16)hi[3];
                av[mi] = a;
            }
            #pragma unroll
            for (int ni = 0; ni < 4; ++ni) {
                int r = waveN * 64 + ni * 16 + (lane & 15);
                bv[ni] = *(const bf16x8*)&Bs[r * 64 + ((kc8 ^ (r & 7)) << 3)];
            }
            #pragma unroll
            for (int mi = 0; mi < 4; ++mi)
                #pragma unroll
                for (int ni = 0; ni < 4; ++ni)
                    acc[mi][ni] = mfma16x16x32(av[mi], bv[ni], acc[mi][ni]);
        }
        __syncthreads();
    }

    const int rb = (lane >> 4) << 2;
    const int cb = lane & 15;
    if constexpr (MODE == 1) {
        #pragma unroll
        for (int mi = 0; mi < 4; ++mi)
            #pragma unroll
            for (int ni = 0; ni < 4; ++ni) {
                int lr = waveM * 64 + mi * 16 + rb;
                int lc = waveN * 64 + ni * 16 + cb;
                #pragma unroll
                for (int rr = 0; rr < 4; ++rr)
                    Cb[(size_t)(crow0 + lr + rr) * Dc + col0 + lc] = (__bf16)tanhf(acc[mi][ni][rr]);
            }
    } else {
        __bf16* T = (__bf16*)smem;           // [128][136] transpose staging (pad: stride 272B)
        #pragma unroll
        for (int mi = 0; mi < 4; ++mi)
            #pragma unroll
            for (int ni = 0; ni < 4; ++ni) {
                int lr = waveM * 64 + mi * 16 + rb;
                int lc = waveN * 64 + ni * 16 + cb;
                #pragma unroll
                for (int rr = 0; rr < 4; ++rr) {
                    __bf16 h = (__bf16)acc[mi][ni][rr];
                    Cb[(size_t)(crow0 + lr + rr) * Dc + col0 + lc] = h;
                    T[lc * 136 + lr + rr] = h;
                }
            }
        __syncthreads();
        const int bb = crow0 >> 11;          // /2048
        const int s0 = crow0 & 2047;
        #pragma unroll
        for (int i = 0; i < 8; ++i) {
            int n  = i * 16 + (tid >> 4);
            int mo = (tid & 15) * 8;
            bf16x8 v = *(const bf16x8*)&T[n * 136 + mo];
            *(bf16x8*)&CTb[(size_t)bb * Dc * Sc + (size_t)(col0 + n) * Sc + s0 + mo] = v;
        }
    }
}

// ---- row softmax in place: 16384 rows of 2048 fp32, one block per row ----
__global__ __launch_bounds__(256) void k_softmax(float* __restrict__ attn) {
    float* p = attn + (size_t)blockIdx.x * Sc;
    const int tid = threadIdx.x;
    f32x4 v0 = *(const f32x4*)&p[tid * 8];
    f32x4 v1 = *(const f32x4*)&p[tid * 8 + 4];
    float m = fmaxf(fmaxf(fmaxf(v0[0], v0[1]), fmaxf(v0[2], v0[3])),
                    fmaxf(fmaxf(v1[0], v1[1]), fmaxf(v1[2], v1[3])));
    #pragma unroll
    for (int off = 32; off > 0; off >>= 1) m = fmaxf(m, __shfl_xor(m, off));
    __shared__ float red[8];
    if ((tid & 63) == 0) red[tid >> 6] = m;
    __syncthreads();
    m = fmaxf(fmaxf(red[0], red[1]), fmaxf(red[2], red[3]));
    float e[8];
    float s = 0.f;
    #pragma unroll
    for (int j = 0; j < 4; ++j) { e[j]     = __expf(v0[j] - m); s += e[j];     }
    #pragma unroll
    for (int j = 0; j < 4; ++j) { e[4 + j] = __expf(v1[j] - m); s += e[4 + j]; }
    #pragma unroll
    for (int off = 32; off > 0; off >>= 1) s += __shfl_xor(s, off);
    if ((tid & 63) == 0) red[4 + (tid >> 6)] = s;
    __syncthreads();
    s = (red[4] + red[5]) + (red[6] + red[7]);
    float inv = 1.f / s;
    f32x4 o0, o1;
    #pragma unroll
    for (int j = 0; j < 4; ++j) { o0[j] = e[j] * inv; o1[j] = e[4 + j] * inv; }
    *(f32x4*)&p[tid * 8]     = o0;
    *(f32x4*)&p[tid * 8 + 4] = o1;
}

extern "C" void kernel_launch(void* const* d_in, const int* in_sizes, int n_in,
                              void* d_out, int out_size, void* d_ws, size_t ws_size,
                              hipStream_t stream)
{
    (void)in_sizes; (void)n_in; (void)out_size; (void)ws_size;
    const float* context = (const float*)d_in[0];
    const float* W_in    = (const float*)d_in[1];
    const float* W_out   = (const float*)d_in[2];
    float* out  = (float*)d_out;
    float* attn = out + (size_t)Bc * Sc * Dc;       // [B,S,S] output region (also scores scratch)

    char* ws = (char*)d_ws;
    __bf16* c_bf  = (__bf16*)ws;                                  // [B*S, D]; reused as tanh(ctx)
    __bf16* cT_bf = (__bf16*)(ws + (size_t)Bc * Sc * Dc * 2);     // [B, D, S]
    __bf16* wi_bf = (__bf16*)(ws + (size_t)Bc * Sc * Dc * 4);
    __bf16* wo_bf = (__bf16*)(ws + (size_t)Bc * Sc * Dc * 4 + (size_t)Dc * Dc * 2);

    // W -> bf16
    k_convert_w<<<dim3(Dc * Dc / 256), 256, 0, stream>>>(W_in, W_out, wi_bf, wo_bf);

    // c = context @ W_in^T   (M=16384, N=512, K=512), also emit c^T
    k_gemm_f32a<0><<<dim3(Dc / 128, (Bc * Sc) / 128, 1), 256, 0, stream>>>(
        context, wi_bf, c_bf, cT_bf, Dc, Dc, Dc, 0, 0, 0);

    // scores = c @ c^T per batch -> attn region (raw, pre-softmax)
    k_gemm_bf16<<<dim3(Sc / 128, Sc / 128, Bc), 256, 0, stream>>>(
        c_bf, c_bf, attn, Dc, Dc, Sc, Dc,
        (size_t)Sc * Dc, (size_t)Sc * Dc, (size_t)Sc * Sc);

    // softmax rows in place
    k_softmax<<<dim3(Bc * Sc), 256, 0, stream>>>(attn);

    // ctx = attn @ c ; tanh -> bf16 (reuse c_bf buffer)
    k_gemm_f32a<1><<<dim3(Dc / 128, Sc / 128, Bc), 256, 0, stream>>>(
        attn, cT_bf, c_bf, nullptr, Sc, Sc, Sc,
        (size_t)Sc * Sc, (size_t)Dc * Sc, Sc);

    // out = tanh(ctx) @ W_out^T  (M=16384, N=512, K=512)
    k_gemm_bf16<<<dim3(Dc / 128, (Bc * Sc) / 128, 1), 256, 0, stream>>>(
        c_bf, wo_bf, out, Dc, Dc, Dc, Dc, 0, 0, 0);
}

// Round 2
// 209.405 us; speedup vs baseline: 1.2348x; 1.2348x over previous
//
#include <hip/hip_runtime.h>
#include <cstdint>
#include <cstddef>

#define Bc 8
#define Sc 2048
#define Dc 512

typedef float f32x4 __attribute__((ext_vector_type(4)));
typedef __bf16 bf16x8 __attribute__((ext_vector_type(8)));

__device__ __forceinline__ void gload_lds16(const void* g, void* l) {
    __builtin_amdgcn_global_load_lds((const __attribute__((address_space(1))) void*)g,
                                     (__attribute__((address_space(3))) void*)l, 16, 0, 0);
}

__device__ __forceinline__ f32x4 mfma16x16x32(bf16x8 a, bf16x8 b, f32x4 c) {
    return __builtin_amdgcn_mfma_f32_16x16x32_bf16(a, b, c, 0, 0, 0);
}

// ---- convert W_in / W_out to bf16 (512*512 each) ----
__global__ void k_convert_w(const float* __restrict__ wi, const float* __restrict__ wo,
                            __bf16* __restrict__ wib, __bf16* __restrict__ wob) {
    int i = blockIdx.x * 256 + threadIdx.x;   // grid sized exactly Dc*Dc/256
    wib[i] = (__bf16)wi[i];
    wob[i] = (__bf16)wo[i];
}

// ---- bf16 GEMM: tile 128x128x64, 4 waves.
//      MODE 0: C fp32 = A * Bt^T      MODE 1: Cb bf16 = tanh(A * Bt^T) ----
template <int MODE>
__global__ __launch_bounds__(256) void k_gemm_bf16(
        const __bf16* __restrict__ A, const __bf16* __restrict__ Bt,
        float* __restrict__ C, __bf16* __restrict__ Cb,
        int lda, int ldb, int ldc, int K,
        size_t aOffZ, size_t bOffZ, size_t cOffZ)
{
    __shared__ __bf16 smem[2 * 128 * 64];
    __bf16* As = smem;
    __bf16* Bs = smem + 128 * 64;
    const int tid  = threadIdx.x;
    const int wave = tid >> 6, lane = tid & 63;
    const int waveM = wave >> 1, waveN = wave & 1;
    const int row0 = blockIdx.y * 128;
    const int col0 = blockIdx.x * 128;
    A  += (size_t)blockIdx.z * aOffZ;
    Bt += (size_t)blockIdx.z * bOffZ;
    if constexpr (MODE == 0) C  += (size_t)blockIdx.z * cOffZ;
    else                     Cb += (size_t)blockIdx.z * cOffZ;

    f32x4 acc[4][4] = {};

    for (int k0 = 0; k0 < K; k0 += 64) {
        // stage A,B [128][64] bf16; linear LDS dest, XOR-swizzled global source (16B chunks)
        #pragma unroll
        for (int i = 0; i < 4; ++i) {
            int flat = i * 2048 + wave * 512 + lane * 8;
            int r  = flat >> 6;
            int cc = (flat >> 3) & 7;
            int gc = (cc ^ (r & 7)) << 3;
            gload_lds16(A  + (size_t)(row0 + r) * lda + k0 + gc, As + i * 2048 + wave * 512);
            gload_lds16(Bt + (size_t)(col0 + r) * ldb + k0 + gc, Bs + i * 2048 + wave * 512);
        }
        __syncthreads();
        #pragma unroll
        for (int ks = 0; ks < 2; ++ks) {
            const int kc = ks * 4 + (lane >> 4);   // 8-elem chunk index
            bf16x8 av[4], bv[4];
            #pragma unroll
            for (int mi = 0; mi < 4; ++mi) {
                int r = waveM * 64 + mi * 16 + (lane & 15);
                av[mi] = *(const bf16x8*)&As[r * 64 + ((kc ^ (r & 7)) << 3)];
            }
            #pragma unroll
            for (int ni = 0; ni < 4; ++ni) {
                int r = waveN * 64 + ni * 16 + (lane & 15);
                bv[ni] = *(const bf16x8*)&Bs[r * 64 + ((kc ^ (r & 7)) << 3)];
            }
            #pragma unroll
            for (int mi = 0; mi < 4; ++mi)
                #pragma unroll
                for (int ni = 0; ni < 4; ++ni)
                    acc[mi][ni] = mfma16x16x32(av[mi], bv[ni], acc[mi][ni]);
        }
        __syncthreads();
    }

    const int rb = (lane >> 4) << 2;
    const int cb = lane & 15;
    #pragma unroll
    for (int mi = 0; mi < 4; ++mi)
        #pragma unroll
        for (int ni = 0; ni < 4; ++ni) {
            int gr = row0 + waveM * 64 + mi * 16 + rb;
            int gc = col0 + waveN * 64 + ni * 16 + cb;
            #pragma unroll
            for (int rr = 0; rr < 4; ++rr) {
                if constexpr (MODE == 0)
                    C[(size_t)(gr + rr) * ldc + gc] = acc[mi][ni][rr];
                else
                    Cb[(size_t)(gr + rr) * ldc + gc] = (__bf16)tanhf(acc[mi][ni][rr]);
            }
        }
}

// ---- fp32-A, bf16-B GEMM. MODE 0: write bf16 C and bf16 C^T (c-projection)
//                           MODE 1: write bf16 tanh(C)        (fallback PV)  ----
template <int MODE>
__global__ __launch_bounds__(256) void k_gemm_f32a(
        const float* __restrict__ A, const __bf16* __restrict__ Bt,
        __bf16* __restrict__ Cb, __bf16* __restrict__ CTb,
        int lda, int ldb, int K, size_t aOffZ, size_t bOffZ, int crowPerZ)
{
    __shared__ char smem[49152];
    float*  Asf = (float*)smem;              // [128][64] fp32 (32 KiB)
    __bf16* Bs  = (__bf16*)(smem + 32768);   // [128][64] bf16 (16 KiB)
    const int tid  = threadIdx.x;
    const int wave = tid >> 6, lane = tid & 63;
    const int waveM = wave >> 1, waveN = wave & 1;
    const int row0 = blockIdx.y * 128;
    const int col0 = blockIdx.x * 128;
    A  += (size_t)blockIdx.z * aOffZ;
    Bt += (size_t)blockIdx.z * bOffZ;
    const int crow0 = blockIdx.z * crowPerZ + row0;

    f32x4 acc[4][4] = {};

    for (int k0 = 0; k0 < K; k0 += 64) {
        #pragma unroll
        for (int i = 0; i < 8; ++i) {        // A fp32: 16 chunks/row of 4 floats
            int flat = i * 1024 + wave * 256 + lane * 4;
            int r  = flat >> 6;
            int cc = (flat >> 2) & 15;
            int gc = (cc ^ (r & 15)) << 2;
            gload_lds16(A + (size_t)(row0 + r) * lda + k0 + gc, Asf + i * 1024 + wave * 256);
        }
        #pragma unroll
        for (int i = 0; i < 4; ++i) {        // B bf16: 8 chunks/row of 8 elems
            int flat = i * 2048 + wave * 512 + lane * 8;
            int r  = flat >> 6;
            int cc = (flat >> 3) & 7;
            int gc = (cc ^ (r & 7)) << 3;
            gload_lds16(Bt + (size_t)(col0 + r) * ldb + k0 + gc, Bs + i * 2048 + wave * 512);
        }
        __syncthreads();
        #pragma unroll
        for (int ks = 0; ks < 2; ++ks) {
            const int kc8 = ks * 4 + (lane >> 4);
            const int kc4 = kc8 << 1;
            bf16x8 av[4], bv[4];
            #pragma unroll
            for (int mi = 0; mi < 4; ++mi) {
                int r  = waveM * 64 + mi * 16 + (lane & 15);
                int r4 = r & 15;
                f32x4 lo = *(const f32x4*)&Asf[r * 64 + (((kc4    ) ^ r4) << 2)];
                f32x4 hi = *(const f32x4*)&Asf[r * 64 + (((kc4 + 1) ^ r4) << 2)];
                bf16x8 a;
                a[0] = (__bf16)lo[0]; a[1] = (__bf16)lo[1]; a[2] = (__bf16)lo[2]; a[3] = (__bf16)lo[3];
                a[4] = (__bf16)hi[0]; a[5] = (__bf16)hi[1]; a[6] = (__bf16)hi[2]; a[7] = (__bf16)hi[3];
                av[mi] = a;
            }
            #pragma unroll
            for (int ni = 0; ni < 4; ++ni) {
                int r = waveN * 64 + ni * 16 + (lane & 15);
                bv[ni] = *(const bf16x8*)&Bs[r * 64 + ((kc8 ^ (r & 7)) << 3)];
            }
            #pragma unroll
            for (int mi = 0; mi < 4; ++mi)
                #pragma unroll
                for (int ni = 0; ni < 4; ++ni)
                    acc[mi][ni] = mfma16x16x32(av[mi], bv[ni], acc[mi][ni]);
        }
        __syncthreads();
    }

    const int rb = (lane >> 4) << 2;
    const int cb = lane & 15;
    if constexpr (MODE == 1) {
        #pragma unroll
        for (int mi = 0; mi < 4; ++mi)
            #pragma unroll
            for (int ni = 0; ni < 4; ++ni) {
                int lr = waveM * 64 + mi * 16 + rb;
                int lc = waveN * 64 + ni * 16 + cb;
                #pragma unroll
                for (int rr = 0; rr < 4; ++rr)
                    Cb[(size_t)(crow0 + lr + rr) * Dc + col0 + lc] = (__bf16)tanhf(acc[mi][ni][rr]);
            }
    } else {
        __bf16* T = (__bf16*)smem;           // [128][136] transpose staging (pad: stride 272B)
        #pragma unroll
        for (int mi = 0; mi < 4; ++mi)
            #pragma unroll
            for (int ni = 0; ni < 4; ++ni) {
                int lr = waveM * 64 + mi * 16 + rb;
                int lc = waveN * 64 + ni * 16 + cb;
                #pragma unroll
                for (int rr = 0; rr < 4; ++rr) {
                    __bf16 h = (__bf16)acc[mi][ni][rr];
                    Cb[(size_t)(crow0 + lr + rr) * Dc + col0 + lc] = h;
                    T[lc * 136 + lr + rr] = h;
                }
            }
        __syncthreads();
        const int bb = crow0 >> 11;          // /2048
        const int s0 = crow0 & 2047;
        #pragma unroll
        for (int i = 0; i < 8; ++i) {
            int n  = i * 16 + (tid >> 4);
            int mo = (tid & 15) * 8;
            bf16x8 v = *(const bf16x8*)&T[n * 136 + mo];
            *(bf16x8*)&CTb[(size_t)bb * Dc * Sc + (size_t)(col0 + n) * Sc + s0 + mo] = v;
        }
    }
}

// ---- row softmax in place (+ optional bf16 copy): 16384 rows of 2048 fp32 ----
__global__ __launch_bounds__(256) void k_softmax(float* __restrict__ attn,
                                                 __bf16* __restrict__ attn_bf) {
    float* p = attn + (size_t)blockIdx.x * Sc;
    const int tid = threadIdx.x;
    f32x4 v0 = *(const f32x4*)&p[tid * 8];
    f32x4 v1 = *(const f32x4*)&p[tid * 8 + 4];
    float m = fmaxf(fmaxf(fmaxf(v0[0], v0[1]), fmaxf(v0[2], v0[3])),
                    fmaxf(fmaxf(v1[0], v1[1]), fmaxf(v1[2], v1[3])));
    #pragma unroll
    for (int off = 32; off > 0; off >>= 1) m = fmaxf(m, __shfl_xor(m, off));
    __shared__ float red[8];
    if ((tid & 63) == 0) red[tid >> 6] = m;
    __syncthreads();
    m = fmaxf(fmaxf(red[0], red[1]), fmaxf(red[2], red[3]));
    float e[8];
    float s = 0.f;
    #pragma unroll
    for (int j = 0; j < 4; ++j) { e[j]     = __expf(v0[j] - m); s += e[j];     }
    #pragma unroll
    for (int j = 0; j < 4; ++j) { e[4 + j] = __expf(v1[j] - m); s += e[4 + j]; }
    #pragma unroll
    for (int off = 32; off > 0; off >>= 1) s += __shfl_xor(s, off);
    if ((tid & 63) == 0) red[4 + (tid >> 6)] = s;
    __syncthreads();
    s = (red[4] + red[5]) + (red[6] + red[7]);
    float inv = 1.f / s;
    f32x4 o0, o1;
    bf16x8 ob;
    #pragma unroll
    for (int j = 0; j < 4; ++j) {
        o0[j] = e[j] * inv;     ob[j]     = (__bf16)o0[j];
        o1[j] = e[4 + j] * inv; ob[4 + j] = (__bf16)o1[j];
    }
    *(f32x4*)&p[tid * 8]     = o0;
    *(f32x4*)&p[tid * 8 + 4] = o1;
    if (attn_bf)
        *(bf16x8*)&attn_bf[(size_t)blockIdx.x * Sc + tid * 8] = ob;
}

extern "C" void kernel_launch(void* const* d_in, const int* in_sizes, int n_in,
                              void* d_out, int out_size, void* d_ws, size_t ws_size,
                              hipStream_t stream)
{
    (void)in_sizes; (void)n_in; (void)out_size;
    const float* context = (const float*)d_in[0];
    const float* W_in    = (const float*)d_in[1];
    const float* W_out   = (const float*)d_in[2];
    float* out  = (float*)d_out;
    float* attn = out + (size_t)Bc * Sc * Dc;       // [B,S,S] output region (also scores scratch)

    char* ws = (char*)d_ws;
    __bf16* c_bf  = (__bf16*)ws;                                  // [B*S, D]; reused as tanh(ctx)
    __bf16* cT_bf = (__bf16*)(ws + (size_t)Bc * Sc * Dc * 2);     // [B, D, S]
    __bf16* wi_bf = (__bf16*)(ws + (size_t)Bc * Sc * Dc * 4);
    __bf16* wo_bf = (__bf16*)(ws + (size_t)Bc * Sc * Dc * 4 + (size_t)Dc * Dc * 2);
    __bf16* attn_bf = (__bf16*)(ws + (size_t)Bc * Sc * Dc * 4 + (size_t)Dc * Dc * 4);

    const size_t ws_needed = (size_t)Bc * Sc * Dc * 4 + (size_t)Dc * Dc * 4
                           + (size_t)Bc * Sc * Sc * 2;
    const bool use_bf_pv = ws_size >= ws_needed;

    // W -> bf16
    k_convert_w<<<dim3(Dc * Dc / 256), 256, 0, stream>>>(W_in, W_out, wi_bf, wo_bf);

    // c = context @ W_in^T   (M=16384, N=512, K=512), also emit c^T
    k_gemm_f32a<0><<<dim3(Dc / 128, (Bc * Sc) / 128, 1), 256, 0, stream>>>(
        context, wi_bf, c_bf, cT_bf, Dc, Dc, Dc, 0, 0, 0);

    // scores = c @ c^T per batch -> attn region (raw, pre-softmax)
    k_gemm_bf16<0><<<dim3(Sc / 128, Sc / 128, Bc), 256, 0, stream>>>(
        c_bf, c_bf, attn, nullptr, Dc, Dc, Sc, Dc,
        (size_t)Sc * Dc, (size_t)Sc * Dc, (size_t)Sc * Sc);

    // softmax rows in place, plus bf16 copy for the PV GEMM
    k_softmax<<<dim3(Bc * Sc), 256, 0, stream>>>(attn, use_bf_pv ? attn_bf : nullptr);

    // ctx = attn @ c ; tanh -> bf16 (reuse c_bf buffer)
    if (use_bf_pv) {
        k_gemm_bf16<1><<<dim3(Dc / 128, Sc / 128, Bc), 256, 0, stream>>>(
            attn_bf, cT_bf, nullptr, c_bf, Sc, Sc, Dc, Sc,
            (size_t)Sc * Sc, (size_t)Dc * Sc, (size_t)Sc * Dc);
    } else {
        k_gemm_f32a<1><<<dim3(Dc / 128, Sc / 128, Bc), 256, 0, stream>>>(
            attn, cT_bf, c_bf, nullptr, Sc, Sc, Sc,
            (size_t)Sc * Sc, (size_t)Dc * Sc, Sc);
    }

    // out = tanh(ctx) @ W_out^T  (M=16384, N=512, K=512)
    k_gemm_bf16<0><<<dim3(Dc / 128, (Bc * Sc) / 128, 1), 256, 0, stream>>>(
        c_bf, wo_bf, out, nullptr, Dc, Dc, Dc, Dc, 0, 0, 0);
}

// Round 3
// 203.071 us; speedup vs baseline: 1.2733x; 1.0312x over previous
//
#include <hip/hip_runtime.h>
#include <cstdint>
#include <cstddef>

#define Bc 8
#define Sc 2048
#define Dc 512

typedef float f32x4 __attribute__((ext_vector_type(4)));
typedef __bf16 bf16x8 __attribute__((ext_vector_type(8)));

__device__ __forceinline__ void gload_lds16(const void* g, void* l) {
    __builtin_amdgcn_global_load_lds((const __attribute__((address_space(1))) void*)g,
                                     (__attribute__((address_space(3))) void*)l, 16, 0, 0);
}

__device__ __forceinline__ f32x4 mfma16x16x32(bf16x8 a, bf16x8 b, f32x4 c) {
    return __builtin_amdgcn_mfma_f32_16x16x32_bf16(a, b, c, 0, 0, 0);
}

// ---- convert W_in / W_out to bf16 (512*512 each) ----
__global__ void k_convert_w(const float* __restrict__ wi, const float* __restrict__ wo,
                            __bf16* __restrict__ wib, __bf16* __restrict__ wob) {
    int i = blockIdx.x * 256 + threadIdx.x;   // grid sized exactly Dc*Dc/256
    wib[i] = (__bf16)wi[i];
    wob[i] = (__bf16)wo[i];
}

// ---- bf16 GEMM: C(fp32)[M,N] = A[M,K]*Bt[N,K]^T, tile 128x128x64, 4 waves.
//      STATS: also emit per-(row, col-tile) softmax partials {rowmax, sum exp(x-rowmax)} ----
template <bool STATS>
__global__ __launch_bounds__(256) void k_gemm_bf16(
        const __bf16* __restrict__ A, const __bf16* __restrict__ Bt,
        float* __restrict__ C, float2* __restrict__ stats,
        int lda, int ldb, int ldc, int K,
        size_t aOffZ, size_t bOffZ, size_t cOffZ)
{
    __shared__ alignas(16) __bf16 smem[2 * 128 * 64];
    __bf16* As = smem;
    __bf16* Bs = smem + 128 * 64;
    const int tid  = threadIdx.x;
    const int wave = tid >> 6, lane = tid & 63;
    const int waveM = wave >> 1, waveN = wave & 1;
    const int row0 = blockIdx.y * 128;
    const int col0 = blockIdx.x * 128;
    A  += (size_t)blockIdx.z * aOffZ;
    Bt += (size_t)blockIdx.z * bOffZ;
    C  += (size_t)blockIdx.z * cOffZ;

    f32x4 acc[4][4] = {};

    for (int k0 = 0; k0 < K; k0 += 64) {
        #pragma unroll
        for (int i = 0; i < 4; ++i) {
            int flat = i * 2048 + wave * 512 + lane * 8;
            int r  = flat >> 6;
            int cc = (flat >> 3) & 7;
            int gc = (cc ^ (r & 7)) << 3;
            gload_lds16(A  + (size_t)(row0 + r) * lda + k0 + gc, As + i * 2048 + wave * 512);
            gload_lds16(Bt + (size_t)(col0 + r) * ldb + k0 + gc, Bs + i * 2048 + wave * 512);
        }
        __syncthreads();
        #pragma unroll
        for (int ks = 0; ks < 2; ++ks) {
            const int kc = ks * 4 + (lane >> 4);   // 8-elem chunk index
            bf16x8 av[4], bv[4];
            #pragma unroll
            for (int mi = 0; mi < 4; ++mi) {
                int r = waveM * 64 + mi * 16 + (lane & 15);
                av[mi] = *(const bf16x8*)&As[r * 64 + ((kc ^ (r & 7)) << 3)];
            }
            #pragma unroll
            for (int ni = 0; ni < 4; ++ni) {
                int r = waveN * 64 + ni * 16 + (lane & 15);
                bv[ni] = *(const bf16x8*)&Bs[r * 64 + ((kc ^ (r & 7)) << 3)];
            }
            #pragma unroll
            for (int mi = 0; mi < 4; ++mi)
                #pragma unroll
                for (int ni = 0; ni < 4; ++ni)
                    acc[mi][ni] = mfma16x16x32(av[mi], bv[ni], acc[mi][ni]);
        }
        __syncthreads();
    }

    const int rb = (lane >> 4) << 2;
    const int cb = lane & 15;
    #pragma unroll
    for (int mi = 0; mi < 4; ++mi)
        #pragma unroll
        for (int ni = 0; ni < 4; ++ni) {
            int gr = row0 + waveM * 64 + mi * 16 + rb;
            int gc = col0 + waveN * 64 + ni * 16 + cb;
            #pragma unroll
            for (int rr = 0; rr < 4; ++rr)
                C[(size_t)(gr + rr) * ldc + gc] = acc[mi][ni][rr];
        }

    if constexpr (STATS) {
        // per-row (over this block's 128 cols) max and sum of exp(x - max)
        float2* sm = (float2*)smem;          // [2 waveN][128 rows], smem free after K loop
        #pragma unroll
        for (int mi = 0; mi < 4; ++mi)
            #pragma unroll
            for (int rr = 0; rr < 4; ++rr) {
                float mx = fmaxf(fmaxf(acc[mi][0][rr], acc[mi][1][rr]),
                                 fmaxf(acc[mi][2][rr], acc[mi][3][rr]));
                #pragma unroll
                for (int off = 1; off < 16; off <<= 1) mx = fmaxf(mx, __shfl_xor(mx, off));
                float zs = 0.f;
                #pragma unroll
                for (int ni = 0; ni < 4; ++ni) zs += __expf(acc[mi][ni][rr] - mx);
                #pragma unroll
                for (int off = 1; off < 16; off <<= 1) zs += __shfl_xor(zs, off);
                if ((lane & 15) == 0)
                    sm[waveN * 128 + waveM * 64 + mi * 16 + rb + rr] = make_float2(mx, zs);
            }
        __syncthreads();
        if (tid < 128) {
            float2 a2 = sm[tid], b2 = sm[128 + tid];
            float M = fmaxf(a2.x, b2.x);
            float Z = a2.y * __expf(a2.x - M) + b2.y * __expf(b2.x - M);
            stats[((size_t)blockIdx.z * Sc + row0 + tid) * 16 + blockIdx.x] = make_float2(M, Z);
        }
    }
}

// ---- combine per-tile stats -> per-row {max, 1/Z} ----
__global__ __launch_bounds__(256) void k_stat_combine(const float2* __restrict__ stats,
                                                      float2* __restrict__ rowstat) {
    int r = blockIdx.x * 256 + threadIdx.x;   // grid = 16384/256
    float2 s[16];
    #pragma unroll
    for (int i = 0; i < 16; ++i) s[i] = stats[(size_t)r * 16 + i];
    float M = s[0].x;
    #pragma unroll
    for (int i = 1; i < 16; ++i) M = fmaxf(M, s[i].x);
    float Z = 0.f;
    #pragma unroll
    for (int i = 0; i < 16; ++i) Z += s[i].y * __expf(s[i].x - M);
    rowstat[r] = make_float2(M, 1.f / Z);
}

// ---- fused softmax + PV: reads raw scores, writes normalized attn (in place) and
//      tanh(attn @ c) bf16. Block = 64 rows x 512 D-cols, 512 threads, 8 waves. ----
__global__ __launch_bounds__(512) void k_pv_fused(
        float* __restrict__ attn,            // [B][S][S]: raw scores in, softmax out
        const __bf16* __restrict__ cT,       // [B][D][S]
        const float2* __restrict__ rowstat,  // [B*S] {m, 1/Z}
        __bf16* __restrict__ ctx)            // [B*S][D] tanh(attn @ c)
{
    __shared__ alignas(16) __bf16 As[64 * 64];    //  8 KiB (XOR-swizzled, reg-staged)
    __shared__ alignas(16) __bf16 Bs[512 * 64];   // 64 KiB (gload_lds, pre-swizzled src)
    const int tid  = threadIdx.x;
    const int wave = tid >> 6, lane = tid & 63;
    const int b    = blockIdx.y;
    const int row0 = blockIdx.x * 64;
    float* sc = attn + (size_t)b * Sc * Sc;
    const __bf16* Bt = cT + (size_t)b * Dc * Sc;

    // A staging: thread owns 8 fp32 of one row per K-step
    const int ar = tid >> 3;            // 0..63
    const int ac = (tid & 7) * 8;       // 0..56
    const float2 st = rowstat[b * Sc + row0 + ar];
    const float m_row = st.x, zinv = st.y;
    const int c8a  = ac >> 3;
    const int aoff = ar * 64 + ((c8a ^ (ar & 7)) << 3);

    f32x4 acc[4][4] = {};               // wave tile: 64 rows x 64 cols (cols wave*64..)

    // prefetch first score tile
    f32x4 s0 = *(const f32x4*)&sc[(size_t)(row0 + ar) * Sc + ac];
    f32x4 s1 = *(const f32x4*)&sc[(size_t)(row0 + ar) * Sc + ac + 4];

    for (int kt = 0; kt < Sc; kt += 64) {
        // stage B: cT tile [512][64] bf16 via global_load_lds (linear dest, swizzled src)
        #pragma unroll
        for (int i = 0; i < 8; ++i) {
            int chunk = i * 512 + wave * 64 + lane;
            int r  = chunk >> 3;
            int cc = chunk & 7;
            gload_lds16(Bt + (size_t)r * Sc + kt + ((cc ^ (r & 7)) << 3),
                        Bs + (size_t)(i * 512 + wave * 64) * 8);
        }
        // normalize prefetched scores, write attn in place, stage A as bf16
        f32x4 p0, p1;
        #pragma unroll
        for (int j = 0; j < 4; ++j) {
            p0[j] = __expf(s0[j] - m_row) * zinv;
            p1[j] = __expf(s1[j] - m_row) * zinv;
        }
        *(f32x4*)&sc[(size_t)(row0 + ar) * Sc + kt + ac]     = p0;
        *(f32x4*)&sc[(size_t)(row0 + ar) * Sc + kt + ac + 4] = p1;
        bf16x8 pb;
        #pragma unroll
        for (int j = 0; j < 4; ++j) { pb[j] = (__bf16)p0[j]; pb[4 + j] = (__bf16)p1[j]; }
        *(bf16x8*)&As[aoff] = pb;
        __syncthreads();
        // prefetch next score tile (hides under MFMA phase)
        if (kt + 64 < Sc) {
            s0 = *(const f32x4*)&sc[(size_t)(row0 + ar) * Sc + kt + 64 + ac];
            s1 = *(const f32x4*)&sc[(size_t)(row0 + ar) * Sc + kt + 64 + ac + 4];
        }
        #pragma unroll
        for (int ks = 0; ks < 2; ++ks) {
            const int kc = ks * 4 + (lane >> 4);
            bf16x8 av[4], bv[4];
            #pragma unroll
            for (int mi = 0; mi < 4; ++mi) {
                int r = mi * 16 + (lane & 15);
                av[mi] = *(const bf16x8*)&As[r * 64 + ((kc ^ (r & 7)) << 3)];
            }
            #pragma unroll
            for (int ni = 0; ni < 4; ++ni) {
                int r = wave * 64 + ni * 16 + (lane & 15);
                bv[ni] = *(const bf16x8*)&Bs[r * 64 + ((kc ^ (r & 7)) << 3)];
            }
            #pragma unroll
            for (int mi = 0; mi < 4; ++mi)
                #pragma unroll
                for (int ni = 0; ni < 4; ++ni)
                    acc[mi][ni] = mfma16x16x32(av[mi], bv[ni], acc[mi][ni]);
        }
        __syncthreads();
    }

    const int rb = (lane >> 4) << 2;
    const int cb = lane & 15;
    #pragma unroll
    for (int mi = 0; mi < 4; ++mi)
        #pragma unroll
        for (int ni = 0; ni < 4; ++ni) {
            int gr = row0 + mi * 16 + rb;
            int gc = wave * 64 + ni * 16 + cb;
            #pragma unroll
            for (int rr = 0; rr < 4; ++rr)
                ctx[(size_t)(b * Sc + gr + rr) * Dc + gc] = (__bf16)tanhf(acc[mi][ni][rr]);
        }
}

// ---- fp32-A, bf16-B GEMM (c-projection): writes bf16 C and bf16 C^T ----
__global__ __launch_bounds__(256) void k_cproj(
        const float* __restrict__ A, const __bf16* __restrict__ Bt,
        __bf16* __restrict__ Cb, __bf16* __restrict__ CTb)
{
    __shared__ alignas(16) char smem[49152];
    float*  Asf = (float*)smem;              // [128][64] fp32 (32 KiB)
    __bf16* Bs  = (__bf16*)(smem + 32768);   // [128][64] bf16 (16 KiB)
    const int tid  = threadIdx.x;
    const int wave = tid >> 6, lane = tid & 63;
    const int waveM = wave >> 1, waveN = wave & 1;
    const int row0 = blockIdx.y * 128;
    const int col0 = blockIdx.x * 128;

    f32x4 acc[4][4] = {};

    for (int k0 = 0; k0 < Dc; k0 += 64) {
        #pragma unroll
        for (int i = 0; i < 8; ++i) {        // A fp32: 16 chunks/row of 4 floats
            int flat = i * 1024 + wave * 256 + lane * 4;
            int r  = flat >> 6;
            int cc = (flat >> 2) & 15;
            int gc = (cc ^ (r & 15)) << 2;
            gload_lds16(A + (size_t)(row0 + r) * Dc + k0 + gc, Asf + i * 1024 + wave * 256);
        }
        #pragma unroll
        for (int i = 0; i < 4; ++i) {        // B bf16: 8 chunks/row of 8 elems
            int flat = i * 2048 + wave * 512 + lane * 8;
            int r  = flat >> 6;
            int cc = (flat >> 3) & 7;
            int gc = (cc ^ (r & 7)) << 3;
            gload_lds16(Bt + (size_t)(col0 + r) * Dc + k0 + gc, Bs + i * 2048 + wave * 512);
        }
        __syncthreads();
        #pragma unroll
        for (int ks = 0; ks < 2; ++ks) {
            const int kc8 = ks * 4 + (lane >> 4);
            const int kc4 = kc8 << 1;
            bf16x8 av[4], bv[4];
            #pragma unroll
            for (int mi = 0; mi < 4; ++mi) {
                int r  = waveM * 64 + mi * 16 + (lane & 15);
                int r4 = r & 15;
                f32x4 lo = *(const f32x4*)&Asf[r * 64 + (((kc4    ) ^ r4) << 2)];
                f32x4 hi = *(const f32x4*)&Asf[r * 64 + (((kc4 + 1) ^ r4) << 2)];
                bf16x8 a;
                a[0] = (__bf16)lo[0]; a[1] = (__bf16)lo[1]; a[2] = (__bf16)lo[2]; a[3] = (__bf16)lo[3];
                a[4] = (__bf16)hi[0]; a[5] = (__bf16)hi[1]; a[6] = (__bf16)hi[2]; a[7] = (__bf16)hi[3];
                av[mi] = a;
            }
            #pragma unroll
            for (int ni = 0; ni < 4; ++ni) {
                int r = waveN * 64 + ni * 16 + (lane & 15);
                bv[ni] = *(const bf16x8*)&Bs[r * 64 + ((kc8 ^ (r & 7)) << 3)];
            }
            #pragma unroll
            for (int mi = 0; mi < 4; ++mi)
                #pragma unroll
                for (int ni = 0; ni < 4; ++ni)
                    acc[mi][ni] = mfma16x16x32(av[mi], bv[ni], acc[mi][ni]);
        }
        __syncthreads();
    }

    const int rb = (lane >> 4) << 2;
    const int cb = lane & 15;
    __bf16* T = (__bf16*)smem;               // [128][136] transpose staging
    #pragma unroll
    for (int mi = 0; mi < 4; ++mi)
        #pragma unroll
        for (int ni = 0; ni < 4; ++ni) {
            int lr = waveM * 64 + mi * 16 + rb;
            int lc = waveN * 64 + ni * 16 + cb;
            #pragma unroll
            for (int rr = 0; rr < 4; ++rr) {
                __bf16 h = (__bf16)acc[mi][ni][rr];
                Cb[(size_t)(row0 + lr + rr) * Dc + col0 + lc] = h;
                T[lc * 136 + lr + rr] = h;
            }
        }
    __syncthreads();
    const int bb = row0 >> 11;               // batch = global row / 2048
    const int s0 = row0 & 2047;
    #pragma unroll
    for (int i = 0; i < 8; ++i) {
        int n  = i * 16 + (tid >> 4);
        int mo = (tid & 15) * 8;
        bf16x8 v = *(const bf16x8*)&T[n * 136 + mo];
        *(bf16x8*)&CTb[(size_t)bb * Dc * Sc + (size_t)(col0 + n) * Sc + s0 + mo] = v;
    }
}

extern "C" void kernel_launch(void* const* d_in, const int* in_sizes, int n_in,
                              void* d_out, int out_size, void* d_ws, size_t ws_size,
                              hipStream_t stream)
{
    (void)in_sizes; (void)n_in; (void)out_size; (void)ws_size;
    const float* context = (const float*)d_in[0];
    const float* W_in    = (const float*)d_in[1];
    const float* W_out   = (const float*)d_in[2];
    float* out  = (float*)d_out;
    float* attn = out + (size_t)Bc * Sc * Dc;       // [B,S,S]: raw scores, then softmax

    char* ws = (char*)d_ws;
    __bf16* c_bf    = (__bf16*)ws;                                 // [B*S, D]; later tanh(ctx)
    __bf16* cT_bf   = (__bf16*)(ws + 16777216);                    // [B, D, S]
    __bf16* wi_bf   = (__bf16*)(ws + 33554432);
    __bf16* wo_bf   = (__bf16*)(ws + 34078720);
    float2* stats   = (float2*)(ws + 34603008);                    // [B*S][16]
    float2* rowstat = (float2*)(ws + 36700160);                    // [B*S]

    // W -> bf16
    k_convert_w<<<dim3(Dc * Dc / 256), 256, 0, stream>>>(W_in, W_out, wi_bf, wo_bf);

    // c = context @ W_in^T  (also emits c^T)
    k_cproj<<<dim3(Dc / 128, (Bc * Sc) / 128), 256, 0, stream>>>(context, wi_bf, c_bf, cT_bf);

    // raw scores = c @ c^T per batch -> attn region, + per-tile softmax partials
    k_gemm_bf16<true><<<dim3(Sc / 128, Sc / 128, Bc), 256, 0, stream>>>(
        c_bf, c_bf, attn, stats, Dc, Dc, Sc, Dc,
        (size_t)Sc * Dc, (size_t)Sc * Dc, (size_t)Sc * Sc);

    // combine partials -> per-row {m, 1/Z}
    k_stat_combine<<<dim3(Bc * Sc / 256), 256, 0, stream>>>(stats, rowstat);

    // fused: normalize scores in place + ctx = softmax @ c, tanh -> bf16 (c_bf reused)
    k_pv_fused<<<dim3(Sc / 64, Bc), 512, 0, stream>>>(attn, cT_bf, rowstat, c_bf);

    // out = tanh(ctx) @ W_out^T
    k_gemm_bf16<false><<<dim3(Dc / 128, (Bc * Sc) / 128, 1), 256, 0, stream>>>(
        c_bf, wo_bf, out, nullptr, Dc, Dc, Dc, Dc, 0, 0, 0);
}

// Round 4
// 191.532 us; speedup vs baseline: 1.3500x; 1.0602x over previous
//
#include <hip/hip_runtime.h>
#include <cstdint>
#include <cstddef>

#define Bc 8
#define Sc 2048
#define Dc 512

typedef float f32x4 __attribute__((ext_vector_type(4)));
typedef __bf16 bf16x8 __attribute__((ext_vector_type(8)));
typedef __bf16 bf16x4 __attribute__((ext_vector_type(4)));

__device__ __forceinline__ void gload_lds16(const void* g, void* l) {
    __builtin_amdgcn_global_load_lds((const __attribute__((address_space(1))) void*)g,
                                     (__attribute__((address_space(3))) void*)l, 16, 0, 0);
}

__device__ __forceinline__ f32x4 mfma16x16x32(bf16x8 a, bf16x8 b, f32x4 c) {
    return __builtin_amdgcn_mfma_f32_16x16x32_bf16(a, b, c, 0, 0, 0);
}

// ---- convert W_in / W_out to bf16 (512*512 each) ----
__global__ void k_convert_w(const float* __restrict__ wi, const float* __restrict__ wo,
                            __bf16* __restrict__ wib, __bf16* __restrict__ wob) {
    int i = blockIdx.x * 256 + threadIdx.x;   // grid sized exactly Dc*Dc/256
    wib[i] = (__bf16)wi[i];
    wob[i] = (__bf16)wo[i];
}

// ---- bf16 GEMM: C(fp32)[M,N] = A[M,K]*Bt[N,K]^T, tile 128x128x64, 4 waves.
//      STATS: 1-D grid, batch = bid&7 (XCD-pinned); also emit per-(row,col-tile)
//      softmax partials {rowmax, sum exp(x-rowmax)} ----
template <bool STATS>
__global__ __launch_bounds__(256) void k_gemm_bf16(
        const __bf16* __restrict__ A, const __bf16* __restrict__ Bt,
        float* __restrict__ C, float2* __restrict__ stats,
        int lda, int ldb, int ldc, int K,
        size_t aOffZ, size_t bOffZ, size_t cOffZ)
{
    __shared__ alignas(16) __bf16 smem[2 * 128 * 64];
    __bf16* As = smem;
    __bf16* Bs = smem + 128 * 64;
    const int tid  = threadIdx.x;
    const int wave = tid >> 6, lane = tid & 63;
    const int waveM = wave >> 1, waveN = wave & 1;
    int row0, col0, bz;
    if constexpr (STATS) {                 // XCD-batch pinning: bid%8 == XCD == batch
        const int bid = blockIdx.x;
        bz   = bid & 7;
        col0 = ((bid >> 3) & 15) * 128;
        row0 = (bid >> 7) * 128;
    } else {
        bz = blockIdx.z; row0 = blockIdx.y * 128; col0 = blockIdx.x * 128;
    }
    A  += (size_t)bz * aOffZ;
    Bt += (size_t)bz * bOffZ;
    C  += (size_t)bz * cOffZ;

    f32x4 acc[4][4] = {};

    for (int k0 = 0; k0 < K; k0 += 64) {
        #pragma unroll
        for (int i = 0; i < 4; ++i) {
            int flat = i * 2048 + wave * 512 + lane * 8;
            int r  = flat >> 6;
            int cc = (flat >> 3) & 7;
            int gc = (cc ^ (r & 7)) << 3;
            gload_lds16(A  + (size_t)(row0 + r) * lda + k0 + gc, As + i * 2048 + wave * 512);
            gload_lds16(Bt + (size_t)(col0 + r) * ldb + k0 + gc, Bs + i * 2048 + wave * 512);
        }
        __syncthreads();
        #pragma unroll
        for (int ks = 0; ks < 2; ++ks) {
            const int kc = ks * 4 + (lane >> 4);   // 8-elem chunk index
            bf16x8 av[4], bv[4];
            #pragma unroll
            for (int mi = 0; mi < 4; ++mi) {
                int r = waveM * 64 + mi * 16 + (lane & 15);
                av[mi] = *(const bf16x8*)&As[r * 64 + ((kc ^ (r & 7)) << 3)];
            }
            #pragma unroll
            for (int ni = 0; ni < 4; ++ni) {
                int r = waveN * 64 + ni * 16 + (lane & 15);
                bv[ni] = *(const bf16x8*)&Bs[r * 64 + ((kc ^ (r & 7)) << 3)];
            }
            #pragma unroll
            for (int mi = 0; mi < 4; ++mi)
                #pragma unroll
                for (int ni = 0; ni < 4; ++ni)
                    acc[mi][ni] = mfma16x16x32(av[mi], bv[ni], acc[mi][ni]);
        }
        __syncthreads();
    }

    const int rb = (lane >> 4) << 2;
    const int cb = lane & 15;
    #pragma unroll
    for (int mi = 0; mi < 4; ++mi)
        #pragma unroll
        for (int ni = 0; ni < 4; ++ni) {
            int gr = row0 + waveM * 64 + mi * 16 + rb;
            int gc = col0 + waveN * 64 + ni * 16 + cb;
            #pragma unroll
            for (int rr = 0; rr < 4; ++rr)
                C[(size_t)(gr + rr) * ldc + gc] = acc[mi][ni][rr];
        }

    if constexpr (STATS) {
        // per-row (over this block's 128 cols) max and sum of exp(x - max)
        float2* sm = (float2*)smem;          // [2 waveN][128 rows], smem free after K loop
        #pragma unroll
        for (int mi = 0; mi < 4; ++mi)
            #pragma unroll
            for (int rr = 0; rr < 4; ++rr) {
                float mx = fmaxf(fmaxf(acc[mi][0][rr], acc[mi][1][rr]),
                                 fmaxf(acc[mi][2][rr], acc[mi][3][rr]));
                #pragma unroll
                for (int off = 1; off < 16; off <<= 1) mx = fmaxf(mx, __shfl_xor(mx, off));
                float zs = 0.f;
                #pragma unroll
                for (int ni = 0; ni < 4; ++ni) zs += __expf(acc[mi][ni][rr] - mx);
                #pragma unroll
                for (int off = 1; off < 16; off <<= 1) zs += __shfl_xor(zs, off);
                if ((lane & 15) == 0)
                    sm[waveN * 128 + waveM * 64 + mi * 16 + rb + rr] = make_float2(mx, zs);
            }
        __syncthreads();
        if (tid < 128) {
            float2 a2 = sm[tid], b2 = sm[128 + tid];
            float M = fmaxf(a2.x, b2.x);
            float Z = a2.y * __expf(a2.x - M) + b2.y * __expf(b2.x - M);
            stats[((size_t)bz * Sc + row0 + tid) * 16 + (col0 >> 7)] = make_float2(M, Z);
        }
    }
}

// ---- combine per-tile stats -> per-row {max, 1/Z} ----
__global__ __launch_bounds__(256) void k_stat_combine(const float2* __restrict__ stats,
                                                      float2* __restrict__ rowstat) {
    int r = blockIdx.x * 256 + threadIdx.x;   // grid = 16384/256
    float2 s[16];
    #pragma unroll
    for (int i = 0; i < 16; ++i) s[i] = stats[(size_t)r * 16 + i];
    float M = s[0].x;
    #pragma unroll
    for (int i = 1; i < 16; ++i) M = fmaxf(M, s[i].x);
    float Z = 0.f;
    #pragma unroll
    for (int i = 0; i < 16; ++i) Z += s[i].y * __expf(s[i].x - M);
    rowstat[r] = make_float2(M, 1.f / Z);
}

// ---- fused softmax + PV: reads raw scores, writes normalized attn (in place) and
//      tanh(attn @ c) bf16. Block = 32 rows x 512 D-cols, 512 threads, 8 waves.
//      1-D grid 512, batch = bid&7 (XCD-pinned); 2 blocks/CU co-resident. ----
__global__ __launch_bounds__(512, 4) void k_pv_fused(
        float* __restrict__ attn,            // [B][S][S]: raw scores in, softmax out
        const __bf16* __restrict__ cT,       // [B][D][S]
        const float2* __restrict__ rowstat,  // [B*S] {m, 1/Z}
        __bf16* __restrict__ ctx)            // [B*S][D] tanh(attn @ c)
{
    __shared__ alignas(16) __bf16 As[32 * 64];    //  4 KiB (XOR-swizzled, reg-staged)
    __shared__ alignas(16) __bf16 Bs[512 * 64];   // 64 KiB (gload_lds, pre-swizzled src)
    const int tid  = threadIdx.x;
    const int wave = tid >> 6, lane = tid & 63;
    const int b    = blockIdx.x & 7;              // == XCD id under %8 round-robin
    const int row0 = (blockIdx.x >> 3) * 32;
    float* sc = attn + (size_t)b * Sc * Sc;
    const __bf16* Bt = cT + (size_t)b * Dc * Sc;

    // A staging: thread owns 4 fp32 of one row per K-step
    const int ar = tid >> 4;            // 0..31
    const int ac = (tid & 15) * 4;      // 0..60
    const float2 st = rowstat[b * Sc + row0 + ar];
    const float m_row = st.x, zinv = st.y;
    const int c8a  = ac >> 3;           // 16B chunk of this thread's 4 bf16
    const int aoff = ar * 64 + ((c8a ^ (ar & 7)) << 3) + (ac & 4);

    f32x4 acc[2][4] = {};               // wave tile: 32 rows x 64 cols (cols wave*64..)

    // prefetch first score tile
    f32x4 s = *(const f32x4*)&sc[(size_t)(row0 + ar) * Sc + ac];

    for (int kt = 0; kt < Sc; kt += 64) {
        // stage B: cT tile [512][64] bf16 via global_load_lds (linear dest, swizzled src)
        #pragma unroll
        for (int i = 0; i < 8; ++i) {
            int chunk = i * 512 + wave * 64 + lane;
            int r  = chunk >> 3;
            int cc = chunk & 7;
            gload_lds16(Bt + (size_t)r * Sc + kt + ((cc ^ (r & 7)) << 3),
                        Bs + (size_t)(i * 512 + wave * 64) * 8);
        }
        // normalize prefetched scores -> bf16 into A-LDS
        f32x4 p;
        #pragma unroll
        for (int j = 0; j < 4; ++j) p[j] = __expf(s[j] - m_row) * zinv;
        bf16x4 pb;
        #pragma unroll
        for (int j = 0; j < 4; ++j) pb[j] = (__bf16)p[j];
        *(bf16x4*)&As[aoff] = pb;
        __syncthreads();
        // store normalized attn + prefetch next tile -- both drain during MFMA phase
        *(f32x4*)&sc[(size_t)(row0 + ar) * Sc + kt + ac] = p;
        if (kt + 64 < Sc)
            s = *(const f32x4*)&sc[(size_t)(row0 + ar) * Sc + kt + 64 + ac];
        #pragma unroll
        for (int ks = 0; ks < 2; ++ks) {
            const int kc = ks * 4 + (lane >> 4);
            bf16x8 av[2], bv[4];
            #pragma unroll
            for (int mi = 0; mi < 2; ++mi) {
                int r = mi * 16 + (lane & 15);
                av[mi] = *(const bf16x8*)&As[r * 64 + ((kc ^ (r & 7)) << 3)];
            }
            #pragma unroll
            for (int ni = 0; ni < 4; ++ni) {
                int r = wave * 64 + ni * 16 + (lane & 15);
                bv[ni] = *(const bf16x8*)&Bs[r * 64 + ((kc ^ (r & 7)) << 3)];
            }
            #pragma unroll
            for (int mi = 0; mi < 2; ++mi)
                #pragma unroll
                for (int ni = 0; ni < 4; ++ni)
                    acc[mi][ni] = mfma16x16x32(av[mi], bv[ni], acc[mi][ni]);
        }
        __syncthreads();
    }

    const int rb = (lane >> 4) << 2;
    const int cb = lane & 15;
    #pragma unroll
    for (int mi = 0; mi < 2; ++mi)
        #pragma unroll
        for (int ni = 0; ni < 4; ++ni) {
            int gr = row0 + mi * 16 + rb;
            int gc = wave * 64 + ni * 16 + cb;
            #pragma unroll
            for (int rr = 0; rr < 4; ++rr)
                ctx[(size_t)(b * Sc + gr + rr) * Dc + gc] = (__bf16)tanhf(acc[mi][ni][rr]);
        }
}

// ---- fp32-A, bf16-B GEMM (c-projection): writes bf16 C and bf16 C^T ----
__global__ __launch_bounds__(256) void k_cproj(
        const float* __restrict__ A, const __bf16* __restrict__ Bt,
        __bf16* __restrict__ Cb, __bf16* __restrict__ CTb)
{
    __shared__ alignas(16) char smem[49152];
    float*  Asf = (float*)smem;              // [128][64] fp32 (32 KiB)
    __bf16* Bs  = (__bf16*)(smem + 32768);   // [128][64] bf16 (16 KiB)
    const int tid  = threadIdx.x;
    const int wave = tid >> 6, lane = tid & 63;
    const int waveM = wave >> 1, waveN = wave & 1;
    const int row0 = blockIdx.y * 128;
    const int col0 = blockIdx.x * 128;

    f32x4 acc[4][4] = {};

    for (int k0 = 0; k0 < Dc; k0 += 64) {
        #pragma unroll
        for (int i = 0; i < 8; ++i) {        // A fp32: 16 chunks/row of 4 floats
            int flat = i * 1024 + wave * 256 + lane * 4;
            int r  = flat >> 6;
            int cc = (flat >> 2) & 15;
            int gc = (cc ^ (r & 15)) << 2;
            gload_lds16(A + (size_t)(row0 + r) * Dc + k0 + gc, Asf + i * 1024 + wave * 256);
        }
        #pragma unroll
        for (int i = 0; i < 4; ++i) {        // B bf16: 8 chunks/row of 8 elems
            int flat = i * 2048 + wave * 512 + lane * 8;
            int r  = flat >> 6;
            int cc = (flat >> 3) & 7;
            int gc = (cc ^ (r & 7)) << 3;
            gload_lds16(Bt + (size_t)(col0 + r) * Dc + k0 + gc, Bs + i * 2048 + wave * 512);
        }
        __syncthreads();
        #pragma unroll
        for (int ks = 0; ks < 2; ++ks) {
            const int kc8 = ks * 4 + (lane >> 4);
            const int kc4 = kc8 << 1;
            bf16x8 av[4], bv[4];
            #pragma unroll
            for (int mi = 0; mi < 4; ++mi) {
                int r  = waveM * 64 + mi * 16 + (lane & 15);
                int r4 = r & 15;
                f32x4 lo = *(const f32x4*)&Asf[r * 64 + (((kc4    ) ^ r4) << 2)];
                f32x4 hi = *(const f32x4*)&Asf[r * 64 + (((kc4 + 1) ^ r4) << 2)];
                bf16x8 a;
                a[0] = (__bf16)lo[0]; a[1] = (__bf16)lo[1]; a[2] = (__bf16)lo[2]; a[3] = (__bf16)lo[3];
                a[4] = (__bf16)hi[0]; a[5] = (__bf16)hi[1]; a[6] = (__bf16)hi[2]; a[7] = (__bf16)hi[3];
                av[mi] = a;
            }
            #pragma unroll
            for (int ni = 0; ni < 4; ++ni) {
                int r = waveN * 64 + ni * 16 + (lane & 15);
                bv[ni] = *(const bf16x8*)&Bs[r * 64 + ((kc8 ^ (r & 7)) << 3)];
            }
            #pragma unroll
            for (int mi = 0; mi < 4; ++mi)
                #pragma unroll
                for (int ni = 0; ni < 4; ++ni)
                    acc[mi][ni] = mfma16x16x32(av[mi], bv[ni], acc[mi][ni]);
        }
        __syncthreads();
    }

    const int rb = (lane >> 4) << 2;
    const int cb = lane & 15;
    __bf16* T = (__bf16*)smem;               // [128][136] transpose staging
    #pragma unroll
    for (int mi = 0; mi < 4; ++mi)
        #pragma unroll
        for (int ni = 0; ni < 4; ++ni) {
            int lr = waveM * 64 + mi * 16 + rb;
            int lc = waveN * 64 + ni * 16 + cb;
            #pragma unroll
            for (int rr = 0; rr < 4; ++rr) {
                __bf16 h = (__bf16)acc[mi][ni][rr];
                Cb[(size_t)(row0 + lr + rr) * Dc + col0 + lc] = h;
                T[lc * 136 + lr + rr] = h;
            }
        }
    __syncthreads();
    const int bb = row0 >> 11;               // batch = global row / 2048
    const int s0 = row0 & 2047;
    #pragma unroll
    for (int i = 0; i < 8; ++i) {
        int n  = i * 16 + (tid >> 4);
        int mo = (tid & 15) * 8;
        bf16x8 v = *(const bf16x8*)&T[n * 136 + mo];
        *(bf16x8*)&CTb[(size_t)bb * Dc * Sc + (size_t)(col0 + n) * Sc + s0 + mo] = v;
    }
}

extern "C" void kernel_launch(void* const* d_in, const int* in_sizes, int n_in,
                              void* d_out, int out_size, void* d_ws, size_t ws_size,
                              hipStream_t stream)
{
    (void)in_sizes; (void)n_in; (void)out_size; (void)ws_size;
    const float* context = (const float*)d_in[0];
    const float* W_in    = (const float*)d_in[1];
    const float* W_out   = (const float*)d_in[2];
    float* out  = (float*)d_out;
    float* attn = out + (size_t)Bc * Sc * Dc;       // [B,S,S]: raw scores, then softmax

    char* ws = (char*)d_ws;
    __bf16* c_bf    = (__bf16*)ws;                                 // [B*S, D]; later tanh(ctx)
    __bf16* cT_bf   = (__bf16*)(ws + 16777216);                    // [B, D, S]
    __bf16* wi_bf   = (__bf16*)(ws + 33554432);
    __bf16* wo_bf   = (__bf16*)(ws + 34078720);
    float2* stats   = (float2*)(ws + 34603008);                    // [B*S][16]
    float2* rowstat = (float2*)(ws + 36700160);                    // [B*S]

    // W -> bf16
    k_convert_w<<<dim3(Dc * Dc / 256), 256, 0, stream>>>(W_in, W_out, wi_bf, wo_bf);

    // c = context @ W_in^T  (also emits c^T)
    k_cproj<<<dim3(Dc / 128, (Bc * Sc) / 128), 256, 0, stream>>>(context, wi_bf, c_bf, cT_bf);

    // raw scores = c @ c^T per batch -> attn region, + per-tile softmax partials
    // 1-D grid, batch = bid&7 -> each XCD keeps one 2MB c-panel L2-resident
    k_gemm_bf16<true><<<dim3(Bc * 16 * 16), 256, 0, stream>>>(
        c_bf, c_bf, attn, stats, Dc, Dc, Sc, Dc,
        (size_t)Sc * Dc, (size_t)Sc * Dc, (size_t)Sc * Sc);

    // combine partials -> per-row {m, 1/Z}
    k_stat_combine<<<dim3(Bc * Sc / 256), 256, 0, stream>>>(stats, rowstat);

    // fused: normalize scores in place + ctx = softmax @ c, tanh -> bf16 (c_bf reused)
    k_pv_fused<<<dim3((Sc / 32) * Bc), 512, 0, stream>>>(attn, cT_bf, rowstat, c_bf);

    // out = tanh(ctx) @ W_out^T
    k_gemm_bf16<false><<<dim3(Dc / 128, (Bc * Sc) / 128, 1), 256, 0, stream>>>(
        c_bf, wo_bf, out, nullptr, Dc, Dc, Dc, Dc, 0, 0, 0);
}